// Round 1
// 306.060 us; speedup vs baseline: 1.0756x; 1.0756x over previous
//
#include <hip/hip_runtime.h>
#include <stdint.h>

// Problem dims (fixed by reference)
#define BB 4
#define SS 2048
#define EE 512
#define HH 1024
// token rows = 8192, ext rows = 2048

typedef _Float16 f16;
typedef __attribute__((ext_vector_type(8))) _Float16 f16x8;
typedef __attribute__((ext_vector_type(4))) _Float16 f16x4;
typedef __attribute__((ext_vector_type(4))) float f32x4;

__device__ __forceinline__ void async16(void* lds, const void* g) {
  __builtin_amdgcn_global_load_lds(
      (const __attribute__((address_space(1))) unsigned int*)g,
      (__attribute__((address_space(3))) unsigned int*)lds, 16, 0, 0);
}

#define MFMA16 __builtin_amdgcn_mfma_f32_16x16x32_f16

// ---------------------------------------------------------------------------
// Legacy 128x128 BT-GEMM core (kept for score/pv kernels, 256-thread blocks).
// TERMS=1: acc += A*Bh          (2 LDS buffers)
// TERMS=3: acc += Ah*Bh + Ah*Bl + Al*Bh  (4 buffers; both split)
// LDS XOR-swizzle: row r's 16B k-chunk c stored at c ^ ((r>>1)&3) ->
// conflict-free ds_read_b128 (verified R2: SQ_LDS_BANK_CONFLICT 1.2e7 -> 0).
// ---------------------------------------------------------------------------
template <int TERMS>
__device__ __forceinline__ void gemm_core(
    const f16* Ah, const f16* Al, const f16* Bh, const f16* Bl, int K, int ld,
    f16* lAh, f16* lAl, f16* lBh, f16* lBl, f32x4 acc[4][4]) {
  const int tid = threadIdx.x;
  const int wave = tid >> 6;
  const int lane = tid & 63;
  const int lrow = lane >> 2;  // 0..15 within 16-row staging group
  const int lcol = (((lane & 3) ^ ((lane >> 3) & 3))) * 8;  // swizzled source chunk
  const int waveM = (wave >> 1) * 64;
  const int waveN = (wave & 1) * 64;
  const int frow = lane & 15;
  const int fk = ((lane >> 4) ^ ((frow >> 1) & 3)) * 8;  // swizzled fragment pos

  for (int k0 = 0; k0 < K; k0 += 32) {
    __syncthreads();  // previous iteration's LDS reads done
#pragma unroll
    for (int i = 0; i < 2; ++i) {
      const int r0 = (wave * 2 + i) * 16;
      const size_t goff = (size_t)(r0 + lrow) * ld + (k0 + lcol);
      async16(&lAh[r0 * 32], Ah + goff);
      async16(&lBh[r0 * 32], Bh + goff);
      if (TERMS >= 2) async16(&lBl[r0 * 32], Bl + goff);
      if (TERMS >= 3) async16(&lAl[r0 * 32], Al + goff);
    }
    __syncthreads();  // staging complete

    f16x8 a[4], bh[4], bl[4], al[4];
#pragma unroll
    for (int i = 0; i < 4; ++i) {
      a[i] = *(const f16x8*)&lAh[(waveM + i * 16 + frow) * 32 + fk];
      bh[i] = *(const f16x8*)&lBh[(waveN + i * 16 + frow) * 32 + fk];
      if (TERMS >= 2) bl[i] = *(const f16x8*)&lBl[(waveN + i * 16 + frow) * 32 + fk];
      if (TERMS >= 3) al[i] = *(const f16x8*)&lAl[(waveM + i * 16 + frow) * 32 + fk];
    }
#pragma unroll
    for (int i = 0; i < 4; ++i)
#pragma unroll
      for (int j = 0; j < 4; ++j) {
        acc[i][j] = MFMA16(a[i], bh[j], acc[i][j], 0, 0, 0);
        if (TERMS >= 2)
          acc[i][j] = MFMA16(a[i], bl[j], acc[i][j], 0, 0, 0);
        if (TERMS >= 3)
          acc[i][j] = MFMA16(al[i], bh[j], acc[i][j], 0, 0, 0);
      }
  }
}

// fp32 -> fp16 cast, both inputs in one launch (hidden then ext)
__global__ __launch_bounds__(256) void cast_kernel(const float* __restrict__ xh32,
                                                   const float* __restrict__ xe32,
                                                   f16* __restrict__ xh,
                                                   f16* __restrict__ xe) {
  const int i = blockIdx.x * 256 + threadIdx.x;
  const int n4h = 8192 * HH / 4;
  const float* src = i < n4h ? xh32 : xe32;
  f16* dst = i < n4h ? xh : xe;
  const int k = i < n4h ? i : i - n4h;
  const float4 v = ((const float4*)src)[k];
  f16x4 o;
  o.x = (f16)v.x; o.y = (f16)v.y; o.z = (f16)v.z; o.w = (f16)v.w;
  ((f16x4*)dst)[k] = o;
}

// Transpose-split W: Wt[n'][k] = W_{n'>>10}[k][n'&1023], n' in [0,3072), fp16 hi+lo
__global__ void wsplit_kernel(const float* __restrict__ Wq, const float* __restrict__ Wk,
                              const float* __restrict__ Wv, f16* __restrict__ wt_hi,
                              f16* __restrict__ wt_lo) {
  __shared__ float tile[32][33];
  const int k0 = blockIdx.x * 32;
  const int n0g = blockIdx.y * 32;
  const int which = n0g >> 10;
  const float* W = which == 0 ? Wq : (which == 1 ? Wk : Wv);
  const int n0 = n0g & 1023;
  const int tx = threadIdx.x, ty = threadIdx.y;
#pragma unroll
  for (int i = 0; i < 32; i += 8)
    tile[ty + i][tx] = W[(size_t)(k0 + ty + i) * 1024 + n0 + tx];
  __syncthreads();
#pragma unroll
  for (int i = 0; i < 32; i += 8) {
    const int np = n0g + ty + i;
    const float v = tile[tx][ty + i];
    const size_t idx = (size_t)np * 1024 + k0 + tx;
    const f16 h = (f16)v;
    wt_hi[idx] = h;
    wt_lo[idx] = (f16)(v - (float)h);
  }
}

// ---------------------------------------------------------------------------
// Projection GEMM, 256x256-tile 8-phase schedule (T2+T3+T4+T5 per m201):
//   8 waves (2M x 4N), BK=64 split in two k-halves of 32, LDS 128 KiB dbuf.
//   Per phase: {ds_read frags | issue 1 half-tile global_load_lds | barrier |
//               setprio(1) 16xMFMA setprio(0) | [counted vmcnt] | barrier}.
//   vmcnt(4) at the two k-half boundaries: per-wave queue holds 8 outstanding
//   loads (Ak0,Bk0,Ak1,Bk1 pairs in fixed order); waiting to <=4 lands exactly
//   the A/B k-half the next two phases read. Never vmcnt(0) except last tile.
// hi/lo precision split folded in as VIRTUAL K=2048: B reads wt_hi for
// k<1024, wt_lo after (A re-read; L2/L3-resident). Same fp32-accum math as
// the old TERMS=2 path.
// LDS swizzle: proven R2 involution, chunk c of 64B row r stored at
// c ^ ((r>>1)&3); pre-swizzled global source + swizzled ds_read (both-sides).
// Grid 448 = heavy(NT=32: token-q 128, ext-ke 32) first for LPT balance,
// then light(NT=16: token-k/v 256, ext-v 32); g&7 = XCD round-robin.
// ---------------------------------------------------------------------------
__global__ __launch_bounds__(512, 2) void proj_kernel(
    const f16* __restrict__ xh, const f16* __restrict__ xe,
    const f16* __restrict__ wt_hi, const f16* __restrict__ wt_lo,
    const float* __restrict__ bq, const float* __restrict__ bk,
    const float* __restrict__ bv, f16* __restrict__ q_hi, f16* __restrict__ q_lo,
    f16* __restrict__ kt, f16* __restrict__ vt,
    f16* __restrict__ ke_hi, f16* __restrict__ ke_lo, f16* __restrict__ veT) {
  const int g = blockIdx.x;
  const int j = g & 7;   // XCD (round-robin assumption)
  const int s = g >> 3;  // 0..55
  int mrow0, colB0;
  bool ext = false, splitB = false;
  if (s < 20) {  // heavy segment, NT=32
    splitB = true;
    if (s < 16) {  // token q: ntile = s>>2 (0..3), mrep = s&3
      colB0 = (s >> 2) * 256;
      mrow0 = ((s & 3) * 8 + j) * 256;
    } else {  // ext ke: ntile = s-16 (0..3), mext = j
      ext = true;
      colB0 = 1024 + (s - 16) * 256;
      mrow0 = j * 256;
    }
  } else {  // light segment, NT=16
    const int s2 = s - 20;
    if (s2 < 32) {  // token k,v: ntile = 4+(s2>>2) (4..11)
      colB0 = (4 + (s2 >> 2)) * 256;
      mrow0 = ((s2 & 3) * 8 + j) * 256;
    } else {  // ext v: ntile = 4+(s2-32) (4..7)
      ext = true;
      colB0 = 1024 + (4 + (s2 - 32)) * 256;
      mrow0 = j * 256;
    }
  }
  const int NT = splitB ? 32 : 16;

  // LDS: A regions [0,32768) f16, B regions [32768,65536).
  // Region (buf,kh) = base + (buf*2+kh)*8192 f16 (16 KB = 256 rows x 32 f16).
  __shared__ f16 lds[65536];  // 128 KiB

  const int tid = threadIdx.x;
  const int wave = tid >> 6, lane = tid & 63;
  const int wm = wave >> 2, wn = wave & 3;
  const int frow = lane & 15, qd = lane >> 4;

  const f16* A0 = (ext ? xe : xh) + (size_t)mrow0 * HH;
  const f16* Bhi = wt_hi + (size_t)colB0 * HH;
  const f16* Blo = wt_lo + (size_t)colB0 * HH;

  // Staging: thread covers region row r = e*128 + tid>>2, stored chunk tid&3,
  // source chunk (tid&3)^((r>>1)&3) (parity of r same for both e).
  const int srow = tid >> 2;
  const int scol = ((tid & 3) ^ ((srow >> 1) & 3)) * 8;
  const size_t gO0 = (size_t)srow * HH + scol;
  const size_t gO1 = (size_t)(128 + srow) * HH + scol;
  const int ldst0 = (wave * 64) * 8;          // f16 units, wave-uniform base
  const int ldst1 = (512 + wave * 64) * 8;

  // Fragment read offsets (f16 units within an 8192-f16 region)
  int offA[8], offB[4];
#pragma unroll
  for (int i = 0; i < 8; ++i) {
    const int r = wm * 128 + i * 16 + frow;
    offA[i] = r * 32 + ((qd ^ ((r >> 1) & 3)) * 8);
  }
#pragma unroll
  for (int jj = 0; jj < 4; ++jj) {
    const int r = wn * 64 + jj * 16 + frow;
    offB[jj] = r * 32 + ((qd ^ ((r >> 1) & 3)) * 8);
  }

  f32x4 acc[8][4];
#pragma unroll
  for (int i = 0; i < 8; ++i)
#pragma unroll
    for (int jj = 0; jj < 4; ++jj)
#pragma unroll
      for (int r = 0; r < 4; ++r) acc[i][jj][r] = 0.0f;

  // Prologue: stage tile 0 in queue order Ak0,Bk0,Ak1,Bk1 (8 issues/wave).
  {
    f16* dA0 = &lds[0];
    f16* dB0 = &lds[32768];
    f16* dA1 = &lds[8192];
    f16* dB1 = &lds[32768 + 8192];
    async16(&dA0[ldst0], A0 + gO0);       async16(&dA0[ldst1], A0 + gO1);
    async16(&dB0[ldst0], Bhi + gO0);      async16(&dB0[ldst1], Bhi + gO1);
    async16(&dA1[ldst0], A0 + 32 + gO0);  async16(&dA1[ldst1], A0 + 32 + gO1);
    async16(&dB1[ldst0], Bhi + 32 + gO0); async16(&dB1[ldst1], Bhi + 32 + gO1);
  }
  asm volatile("s_waitcnt vmcnt(4)" ::: "memory");  // Ak0,Bk0 landed
  __builtin_amdgcn_s_barrier();

  for (int t = 0; t < NT; ++t) {
    const int cur = t & 1, nxt = cur ^ 1;
    const bool st = (t + 1 < NT);
    const int kn = ((t + 1) & 15) * 64;
    const f16* An = A0 + kn;
    const f16* Bn = (((t + 1) & 16) ? Blo : Bhi) + kn;
    const f16* lA0 = &lds[(cur * 2 + 0) * 8192];
    const f16* lB0 = &lds[32768 + (cur * 2 + 0) * 8192];
    const f16* lA1 = &lds[(cur * 2 + 1) * 8192];
    const f16* lB1 = &lds[32768 + (cur * 2 + 1) * 8192];
    f16* sA0 = &lds[(nxt * 2 + 0) * 8192];
    f16* sB0 = &lds[32768 + (nxt * 2 + 0) * 8192];
    f16* sA1 = &lds[(nxt * 2 + 1) * 8192];
    f16* sB1 = &lds[32768 + (nxt * 2 + 1) * 8192];

    f16x8 a[8], b0, b1;

    // ---- phase 0: ks=0, j={0,1}; stage Ak0(t+1)
#pragma unroll
    for (int i = 0; i < 8; ++i) a[i] = *(const f16x8*)&lA0[offA[i]];
    b0 = *(const f16x8*)&lB0[offB[0]];
    b1 = *(const f16x8*)&lB0[offB[1]];
    if (st) { async16(&sA0[ldst0], An + gO0); async16(&sA0[ldst1], An + gO1); }
    __builtin_amdgcn_s_barrier();
    __builtin_amdgcn_s_setprio(1);
#pragma unroll
    for (int i = 0; i < 8; ++i) {
      acc[i][0] = MFMA16(a[i], b0, acc[i][0], 0, 0, 0);
      acc[i][1] = MFMA16(a[i], b1, acc[i][1], 0, 0, 0);
    }
    __builtin_amdgcn_s_setprio(0);
    __builtin_amdgcn_s_barrier();

    // ---- phase 1: ks=0, j={2,3}; stage Bk0(t+1); k-half boundary wait
    b0 = *(const f16x8*)&lB0[offB[2]];
    b1 = *(const f16x8*)&lB0[offB[3]];
    if (st) { async16(&sB0[ldst0], Bn + gO0); async16(&sB0[ldst1], Bn + gO1); }
    __builtin_amdgcn_s_barrier();
    __builtin_amdgcn_s_setprio(1);
#pragma unroll
    for (int i = 0; i < 8; ++i) {
      acc[i][2] = MFMA16(a[i], b0, acc[i][2], 0, 0, 0);
      acc[i][3] = MFMA16(a[i], b1, acc[i][3], 0, 0, 0);
    }
    __builtin_amdgcn_s_setprio(0);
    if (t == NT - 1) {
      asm volatile("s_waitcnt vmcnt(0)" ::: "memory");  // tail: only 2 left
    } else {
      asm volatile("s_waitcnt vmcnt(4)" ::: "memory");  // Ak1,Bk1(t) landed
    }
    __builtin_amdgcn_s_barrier();

    // ---- phase 2: ks=1, j={0,1}; stage Ak1(t+1)
#pragma unroll
    for (int i = 0; i < 8; ++i) a[i] = *(const f16x8*)&lA1[offA[i]];
    b0 = *(const f16x8*)&lB1[offB[0]];
    b1 = *(const f16x8*)&lB1[offB[1]];
    if (st) { async16(&sA1[ldst0], An + 32 + gO0); async16(&sA1[ldst1], An + 32 + gO1); }
    __builtin_amdgcn_s_barrier();
    __builtin_amdgcn_s_setprio(1);
#pragma unroll
    for (int i = 0; i < 8; ++i) {
      acc[i][0] = MFMA16(a[i], b0, acc[i][0], 0, 0, 0);
      acc[i][1] = MFMA16(a[i], b1, acc[i][1], 0, 0, 0);
    }
    __builtin_amdgcn_s_setprio(0);
    __builtin_amdgcn_s_barrier();

    // ---- phase 3: ks=1, j={2,3}; stage Bk1(t+1); tile boundary wait
    b0 = *(const f16x8*)&lB1[offB[2]];
    b1 = *(const f16x8*)&lB1[offB[3]];
    if (st) { async16(&sB1[ldst0], Bn + 32 + gO0); async16(&sB1[ldst1], Bn + 32 + gO1); }
    __builtin_amdgcn_s_barrier();
    __builtin_amdgcn_s_setprio(1);
#pragma unroll
    for (int i = 0; i < 8; ++i) {
      acc[i][2] = MFMA16(a[i], b0, acc[i][2], 0, 0, 0);
      acc[i][3] = MFMA16(a[i], b1, acc[i][3], 0, 0, 0);
    }
    __builtin_amdgcn_s_setprio(0);
    asm volatile("s_waitcnt vmcnt(4)" ::: "memory");  // Ak0,Bk0(t+1) landed
    __builtin_amdgcn_s_barrier();
  }

  // -------------------- epilogue --------------------
  const int er0 = wm * 128 + qd * 4;   // + i*16 + r -> local row (0..255)
  const int ec0 = wn * 64 + frow;      // + jj*16    -> local col (0..255)
  float bias[4];
#pragma unroll
  for (int jj = 0; jj < 4; ++jj) {
    const int c = colB0 + ec0 + jj * 16;
    bias[jj] = c < 1024 ? bq[c] : (c < 2048 ? bk[c - 1024] : bv[c - 2048]);
  }

  if (!ext) {
    if (colB0 < 1024) {  // q: hi+lo (R3-proven scalar row-major stores)
#pragma unroll
      for (int jj = 0; jj < 4; ++jj) {
        const int c = colB0 + ec0 + jj * 16;
#pragma unroll
        for (int i = 0; i < 8; ++i)
#pragma unroll
          for (int r = 0; r < 4; ++r) {
            const int row = mrow0 + er0 + i * 16 + r;
            const float val = acc[i][jj][r] + bias[jj];
            const size_t idx = (size_t)row * HH + c;
            const f16 h = (f16)val;
            q_hi[idx] = h;
            q_lo[idx] = (f16)(val - (float)h);
          }
      }
    } else if (colB0 < 2048) {  // token k
#pragma unroll
      for (int jj = 0; jj < 4; ++jj) {
        const int c = colB0 + ec0 + jj * 16 - 1024;
#pragma unroll
        for (int i = 0; i < 8; ++i)
#pragma unroll
          for (int r = 0; r < 4; ++r) {
            const int row = mrow0 + er0 + i * 16 + r;
            kt[(size_t)row * HH + c] = (f16)(acc[i][jj][r] + bias[jj]);
          }
      }
    } else {  // token v
#pragma unroll
      for (int jj = 0; jj < 4; ++jj) {
        const int c = colB0 + ec0 + jj * 16 - 2048;
#pragma unroll
        for (int i = 0; i < 8; ++i)
#pragma unroll
          for (int r = 0; r < 4; ++r) {
            const int row = mrow0 + er0 + i * 16 + r;
            vt[(size_t)row * HH + c] = (f16)(acc[i][jj][r] + bias[jj]);
          }
      }
    }
  } else {
    if (colB0 < 2048) {  // ext k: hi+lo
#pragma unroll
      for (int jj = 0; jj < 4; ++jj) {
        const int c = colB0 + ec0 + jj * 16 - 1024;
#pragma unroll
        for (int i = 0; i < 8; ++i)
#pragma unroll
          for (int r = 0; r < 4; ++r) {
            const int row = mrow0 + er0 + i * 16 + r;
            const float val = acc[i][jj][r] + bias[jj];
            const size_t idx = (size_t)row * HH + c;
            const f16 h = (f16)val;
            ke_hi[idx] = h;
            ke_lo[idx] = (f16)(val - (float)h);
          }
      }
    } else {  // ext v -> veT[b][h][e], transposed via LDS in two h-halves
      f16* tl = lds;  // [128][264] f16 = 67.6 KB (264*2 = 33*16 B: x8-aligned)
      const int b = mrow0 >> 9, e0 = mrow0 & 511;
      const int h0 = colB0 - 2048;
#pragma unroll
      for (int p = 0; p < 2; ++p) {
        __syncthreads();
        if ((wn >> 1) == p) {
          const int hL = (wn & 1) * 64 + frow;
#pragma unroll
          for (int jj = 0; jj < 4; ++jj)
#pragma unroll
            for (int i = 0; i < 8; ++i)
#pragma unroll
              for (int r = 0; r < 4; ++r) {
                const int e = er0 + i * 16 + r;
                tl[(hL + jj * 16) * 264 + e] = (f16)(acc[i][jj][r] + bias[jj]);
              }
        }
        __syncthreads();
        for (int c = tid; c < 128 * 32; c += 512) {
          const int hL = c >> 5, ch = c & 31;
          const f16x8 v = *(const f16x8*)&tl[hL * 264 + ch * 8];
          *(f16x8*)&veT[(size_t)(b * HH + h0 + p * 128 + hL) * EE + e0 + ch * 8] = v;
        }
      }
    }
  }
}

// Score GEMM, split-K, 3-term: s_part[kh][b][s][e] = q[b,s,kh*512:] . ke[...]
// acc = qh*keh + qh*kel + ql*keh (dropped ql*kel ~ 1e-7 relative).
__global__ __launch_bounds__(256, 4) void score_kernel(
    const f16* __restrict__ q_hi, const f16* __restrict__ q_lo,
    const f16* __restrict__ ke_hi, const f16* __restrict__ ke_lo,
    float* __restrict__ s_part) {
  const int b = blockIdx.z & 3;
  const int khalf = blockIdx.z >> 2;
  const int mtile = blockIdx.y;  // 0..15
  const int ntile = blockIdx.x;  // 0..3
  __shared__ f16 lds[4 * 4096];
  const size_t aoff = ((size_t)b * SS + mtile * 128) * HH + khalf * 512;
  const size_t boff = ((size_t)b * EE + ntile * 128) * HH + khalf * 512;

  f32x4 acc[4][4];
#pragma unroll
  for (int i = 0; i < 4; ++i)
#pragma unroll
    for (int j = 0; j < 4; ++j)
#pragma unroll
      for (int r = 0; r < 4; ++r) acc[i][j][r] = 0.0f;

  gemm_core<3>(q_hi + aoff, q_lo + aoff, ke_hi + boff, ke_lo + boff, 512, HH,
               lds, lds + 4096, lds + 8192, lds + 12288, acc);

  float* dst = s_part + (size_t)khalf * BB * SS * EE;
  const int tid = threadIdx.x, wave = tid >> 6, lane = tid & 63;
  const int waveM = (wave >> 1) * 64, waveN = (wave & 1) * 64;
  const int colIn16 = lane & 15, rowQuad = (lane >> 4) * 4;
#pragma unroll
  for (int j = 0; j < 4; ++j) {
    const int e = ntile * 128 + waveN + j * 16 + colIn16;
#pragma unroll
    for (int i = 0; i < 4; ++i)
#pragma unroll
      for (int r = 0; r < 4; ++r) {
        const int s = mtile * 128 + waveM + i * 16 + rowQuad + r;
        dst[((size_t)b * SS + s) * EE + e] = acc[i][j][r];
      }
  }
}

// Fused selfdot + softmax: s_self = (q_hi+q_lo).kt (fp32 accumulate),
// softmax over [s_self, s_part0+s_part1]; probs -> fp16, p_self -> fp32.
__global__ __launch_bounds__(256) void softmax_kernel(
    const f16* __restrict__ q_hi, const f16* __restrict__ q_lo,
    const f16* __restrict__ kt, const float* __restrict__ s_part,
    f16* __restrict__ probs, float* __restrict__ p_self) {
  const int t = blockIdx.x * 4 + (threadIdx.x >> 6);
  const int lane = threadIdx.x & 63;

  // selfdot
  const size_t base = (size_t)t * HH;
  float ss = 0.f;
#pragma unroll
  for (int it = 0; it < 4; ++it) {
    const int off = it * 256 + lane * 4;
    const f16x4 qh = *(const f16x4*)&q_hi[base + off];
    const f16x4 ql = *(const f16x4*)&q_lo[base + off];
    const f16x4 kh = *(const f16x4*)&kt[base + off];
    ss += ((float)qh.x + (float)ql.x) * (float)kh.x;
    ss += ((float)qh.y + (float)ql.y) * (float)kh.y;
    ss += ((float)qh.z + (float)ql.z) * (float)kh.z;
    ss += ((float)qh.w + (float)ql.w) * (float)kh.w;
  }
#pragma unroll
  for (int m = 32; m > 0; m >>= 1) ss += __shfl_xor(ss, m, 64);

  // softmax over 1 + 512
  const float* r0 = s_part + (size_t)t * EE;
  const float* r1 = s_part + (size_t)BB * SS * EE + (size_t)t * EE;
  const float4 a0 = *(const float4*)&r0[lane * 4];
  const float4 a1 = *(const float4*)&r0[256 + lane * 4];
  const float4 c0 = *(const float4*)&r1[lane * 4];
  const float4 c1 = *(const float4*)&r1[256 + lane * 4];
  const float v0x = a0.x + c0.x, v0y = a0.y + c0.y, v0z = a0.z + c0.z, v0w = a0.w + c0.w;
  const float v1x = a1.x + c1.x, v1y = a1.y + c1.y, v1z = a1.z + c1.z, v1w = a1.w + c1.w;
  float m = fmaxf(fmaxf(fmaxf(v0x, v0y), fmaxf(v0z, v0w)),
                  fmaxf(fmaxf(v1x, v1y), fmaxf(v1z, v1w)));
#pragma unroll
  for (int sh = 32; sh > 0; sh >>= 1) m = fmaxf(m, __shfl_xor(m, sh, 64));
  m = fmaxf(m, ss);
  const float e0 = __expf(v0x - m), e1 = __expf(v0y - m);
  const float e2 = __expf(v0z - m), e3 = __expf(v0w - m);
  const float e4 = __expf(v1x - m), e5 = __expf(v1y - m);
  const float e6 = __expf(v1z - m), e7 = __expf(v1w - m);
  float sum = ((e0 + e1) + (e2 + e3)) + ((e4 + e5) + (e6 + e7));
#pragma unroll
  for (int sh = 32; sh > 0; sh >>= 1) sum += __shfl_xor(sum, sh, 64);
  const float es = __expf(ss - m);
  const float inv = 1.0f / (sum + es);
  f16x4 p0, p1;
  p0.x = (f16)(e0 * inv); p0.y = (f16)(e1 * inv);
  p0.z = (f16)(e2 * inv); p0.w = (f16)(e3 * inv);
  p1.x = (f16)(e4 * inv); p1.y = (f16)(e5 * inv);
  p1.z = (f16)(e6 * inv); p1.w = (f16)(e7 * inv);
  *(f16x4*)&probs[(size_t)t * EE + lane * 4] = p0;
  *(f16x4*)&probs[(size_t)t * EE + 256 + lane * 4] = p1;
  if (lane == 0) p_self[t] = es * inv;
}

// PV GEMM per batch: out[b,s,h] = probs[b,s,:] . v_ext[b,:,h] + p_self*v_tok
__global__ __launch_bounds__(256, 4) void pv_kernel(
    const f16* __restrict__ probs, const f16* __restrict__ veT,
    const float* __restrict__ p_self, const f16* __restrict__ vt,
    float* __restrict__ out) {
  const int b = blockIdx.z;
  const int mtile = blockIdx.y;  // 0..15 (S)
  const int ntile = blockIdx.x;  // 0..7  (H)
  __shared__ f16 lds[2 * 4096];
  const size_t aoff = ((size_t)b * SS + mtile * 128) * EE;
  const size_t boff = ((size_t)b * HH + ntile * 128) * EE;

  f32x4 acc[4][4];
#pragma unroll
  for (int i = 0; i < 4; ++i)
#pragma unroll
    for (int j = 0; j < 4; ++j)
#pragma unroll
      for (int r = 0; r < 4; ++r) acc[i][j][r] = 0.0f;

  gemm_core<1>(probs + aoff, nullptr, veT + boff, nullptr, EE, EE,
               lds, nullptr, lds + 4096, nullptr, acc);

  const int tid = threadIdx.x, wave = tid >> 6, lane = tid & 63;
  const int waveM = (wave >> 1) * 64, waveN = (wave & 1) * 64;
  const int colIn16 = lane & 15, rowQuad = (lane >> 4) * 4;
#pragma unroll
  for (int j = 0; j < 4; ++j) {
    const int h = ntile * 128 + waveN + j * 16 + colIn16;
#pragma unroll
    for (int i = 0; i < 4; ++i)
#pragma unroll
      for (int r = 0; r < 4; ++r) {
        const int s = mtile * 128 + waveM + i * 16 + rowQuad + r;
        const size_t t = (size_t)b * SS + s;
        __builtin_nontemporal_store(
            acc[i][j][r] + p_self[t] * (float)vt[t * HH + h], &out[t * HH + h]);
      }
  }
}

extern "C" void kernel_launch(void* const* d_in, const int* in_sizes, int n_in,
                              void* d_out, int out_size, void* d_ws, size_t ws_size,
                              hipStream_t stream) {
  const float* hidden = (const float*)d_in[0];
  const float* ext    = (const float*)d_in[1];
  const float* Wq = (const float*)d_in[2];
  const float* bq = (const float*)d_in[3];
  const float* Wk = (const float*)d_in[4];
  const float* bk = (const float*)d_in[5];
  const float* Wv = (const float*)d_in[6];
  const float* bv = (const float*)d_in[7];
  float* out = (float*)d_out;

  char* ws = (char*)d_ws;
  size_t off = 0;
  auto alloc = [&](size_t bytes) {
    char* p = ws + off;
    off += (bytes + 255) & ~(size_t)255;
    return p;
  };
  const size_t TOK = 8192, EXT = 2048;
  f16* xh    = (f16*)alloc(TOK * HH * 2);
  f16* xe    = (f16*)alloc(EXT * HH * 2);
  f16* wt_hi = (f16*)alloc(3072ull * HH * 2);
  f16* wt_lo = (f16*)alloc(3072ull * HH * 2);
  f16* q_hi  = (f16*)alloc(TOK * HH * 2);
  f16* q_lo  = (f16*)alloc(TOK * HH * 2);
  f16* kt    = (f16*)alloc(TOK * HH * 2);
  f16* vt    = (f16*)alloc(TOK * HH * 2);
  f16* ke_hi = (f16*)alloc(EXT * HH * 2);
  f16* ke_lo = (f16*)alloc(EXT * HH * 2);
  f16* veT   = (f16*)alloc((size_t)BB * HH * EE * 2);
  float* p_self = (float*)alloc(TOK * 4);
  float* s_part = (float*)alloc(2ull * BB * SS * EE * 4);
  f16* probs    = (f16*)alloc((size_t)BB * SS * EE * 2);

  // 1. cast A-side inputs to fp16 (one launch); transpose+split W hi/lo
  cast_kernel<<<10240, 256, 0, stream>>>(hidden, ext, xh, xe);
  wsplit_kernel<<<dim3(32, 96), dim3(32, 8), 0, stream>>>(Wq, Wk, Wv, wt_hi, wt_lo);

  // 2. fused projection GEMM, 256^2 8-phase counted-vmcnt schedule
  proj_kernel<<<448, 512, 0, stream>>>(
      xh, xe, wt_hi, wt_lo, bq, bk, bv,
      q_hi, q_lo, kt, vt, ke_hi, ke_lo, veT);

  // 3. attention
  score_kernel<<<dim3(4, 16, 8), 256, 0, stream>>>(q_hi, q_lo, ke_hi, ke_lo, s_part);
  softmax_kernel<<<2048, 256, 0, stream>>>(q_hi, q_lo, kt, s_part, probs, p_self);
  pv_kernel<<<dim3(8, 16, 4), 256, 0, stream>>>(probs, veT, p_self, vt, out);
}

// Round 2
// 281.124 us; speedup vs baseline: 1.1710x; 1.0887x over previous
//
#include <hip/hip_runtime.h>
#include <stdint.h>

// Problem dims (fixed by reference)
#define BB 4
#define SS 2048
#define EE 512
#define HH 1024
// token rows = 8192, ext rows = 2048

typedef _Float16 f16;
typedef __attribute__((ext_vector_type(8))) _Float16 f16x8;
typedef __attribute__((ext_vector_type(4))) _Float16 f16x4;
typedef __attribute__((ext_vector_type(4))) float f32x4;

__device__ __forceinline__ void async16(void* lds, const void* g) {
  __builtin_amdgcn_global_load_lds(
      (const __attribute__((address_space(1))) unsigned int*)g,
      (__attribute__((address_space(3))) unsigned int*)lds, 16, 0, 0);
}

#define MFMA16 __builtin_amdgcn_mfma_f32_16x16x32_f16

// fp32 -> fp16 cast, both inputs in one launch (hidden then ext)
__global__ __launch_bounds__(256) void cast_kernel(const float* __restrict__ xh32,
                                                   const float* __restrict__ xe32,
                                                   f16* __restrict__ xh,
                                                   f16* __restrict__ xe) {
  const int i = blockIdx.x * 256 + threadIdx.x;
  const int n4h = 8192 * HH / 4;
  const float* src = i < n4h ? xh32 : xe32;
  f16* dst = i < n4h ? xh : xe;
  const int k = i < n4h ? i : i - n4h;
  const float4 v = ((const float4*)src)[k];
  f16x4 o;
  o.x = (f16)v.x; o.y = (f16)v.y; o.z = (f16)v.z; o.w = (f16)v.w;
  ((f16x4*)dst)[k] = o;
}

// Transpose-split W: Wt[n'][k] = W_{n'>>10}[k][n'&1023], n' in [0,3072), fp16 hi+lo
__global__ void wsplit_kernel(const float* __restrict__ Wq, const float* __restrict__ Wk,
                              const float* __restrict__ Wv, f16* __restrict__ wt_hi,
                              f16* __restrict__ wt_lo) {
  __shared__ float tile[32][33];
  const int k0 = blockIdx.x * 32;
  const int n0g = blockIdx.y * 32;
  const int which = n0g >> 10;
  const float* W = which == 0 ? Wq : (which == 1 ? Wk : Wv);
  const int n0 = n0g & 1023;
  const int tx = threadIdx.x, ty = threadIdx.y;
#pragma unroll
  for (int i = 0; i < 32; i += 8)
    tile[ty + i][tx] = W[(size_t)(k0 + ty + i) * 1024 + n0 + tx];
  __syncthreads();
#pragma unroll
  for (int i = 0; i < 32; i += 8) {
    const int np = n0g + ty + i;
    const float v = tile[tx][ty + i];
    const size_t idx = (size_t)np * 1024 + k0 + tx;
    const f16 h = (f16)v;
    wt_hi[idx] = h;
    wt_lo[idx] = (f16)(v - (float)h);
  }
}

// ---------------------------------------------------------------------------
// Projection GEMM, 256x256-tile 8-phase schedule (unchanged from R1; 112 us,
// MfmaUtil 30%). Critical path is the 48-step quanta bound; revisit later.
// ---------------------------------------------------------------------------
__global__ __launch_bounds__(512, 2) void proj_kernel(
    const f16* __restrict__ xh, const f16* __restrict__ xe,
    const f16* __restrict__ wt_hi, const f16* __restrict__ wt_lo,
    const float* __restrict__ bq, const float* __restrict__ bk,
    const float* __restrict__ bv, f16* __restrict__ q_hi, f16* __restrict__ q_lo,
    f16* __restrict__ kt, f16* __restrict__ vt,
    f16* __restrict__ ke_hi, f16* __restrict__ ke_lo, f16* __restrict__ veT) {
  const int g = blockIdx.x;
  const int j = g & 7;   // XCD (round-robin assumption)
  const int s = g >> 3;  // 0..55
  int mrow0, colB0;
  bool ext = false, splitB = false;
  if (s < 20) {  // heavy segment, NT=32
    splitB = true;
    if (s < 16) {  // token q
      colB0 = (s >> 2) * 256;
      mrow0 = ((s & 3) * 8 + j) * 256;
    } else {  // ext ke
      ext = true;
      colB0 = 1024 + (s - 16) * 256;
      mrow0 = j * 256;
    }
  } else {  // light segment, NT=16
    const int s2 = s - 20;
    if (s2 < 32) {  // token k,v
      colB0 = (4 + (s2 >> 2)) * 256;
      mrow0 = ((s2 & 3) * 8 + j) * 256;
    } else {  // ext v
      ext = true;
      colB0 = 1024 + (4 + (s2 - 32)) * 256;
      mrow0 = j * 256;
    }
  }
  const int NT = splitB ? 32 : 16;

  __shared__ f16 lds[65536];  // 128 KiB

  const int tid = threadIdx.x;
  const int wave = tid >> 6, lane = tid & 63;
  const int wm = wave >> 2, wn = wave & 3;
  const int frow = lane & 15, qd = lane >> 4;

  const f16* A0 = (ext ? xe : xh) + (size_t)mrow0 * HH;
  const f16* Bhi = wt_hi + (size_t)colB0 * HH;
  const f16* Blo = wt_lo + (size_t)colB0 * HH;

  const int srow = tid >> 2;
  const int scol = ((tid & 3) ^ ((srow >> 1) & 3)) * 8;
  const size_t gO0 = (size_t)srow * HH + scol;
  const size_t gO1 = (size_t)(128 + srow) * HH + scol;
  const int ldst0 = (wave * 64) * 8;
  const int ldst1 = (512 + wave * 64) * 8;

  int offA[8], offB[4];
#pragma unroll
  for (int i = 0; i < 8; ++i) {
    const int r = wm * 128 + i * 16 + frow;
    offA[i] = r * 32 + ((qd ^ ((r >> 1) & 3)) * 8);
  }
#pragma unroll
  for (int jj = 0; jj < 4; ++jj) {
    const int r = wn * 64 + jj * 16 + frow;
    offB[jj] = r * 32 + ((qd ^ ((r >> 1) & 3)) * 8);
  }

  f32x4 acc[8][4];
#pragma unroll
  for (int i = 0; i < 8; ++i)
#pragma unroll
    for (int jj = 0; jj < 4; ++jj)
#pragma unroll
      for (int r = 0; r < 4; ++r) acc[i][jj][r] = 0.0f;

  {
    f16* dA0 = &lds[0];
    f16* dB0 = &lds[32768];
    f16* dA1 = &lds[8192];
    f16* dB1 = &lds[32768 + 8192];
    async16(&dA0[ldst0], A0 + gO0);       async16(&dA0[ldst1], A0 + gO1);
    async16(&dB0[ldst0], Bhi + gO0);      async16(&dB0[ldst1], Bhi + gO1);
    async16(&dA1[ldst0], A0 + 32 + gO0);  async16(&dA1[ldst1], A0 + 32 + gO1);
    async16(&dB1[ldst0], Bhi + 32 + gO0); async16(&dB1[ldst1], Bhi + 32 + gO1);
  }
  asm volatile("s_waitcnt vmcnt(4)" ::: "memory");
  __builtin_amdgcn_s_barrier();

  for (int t = 0; t < NT; ++t) {
    const int cur = t & 1, nxt = cur ^ 1;
    const bool st = (t + 1 < NT);
    const int kn = ((t + 1) & 15) * 64;
    const f16* An = A0 + kn;
    const f16* Bn = (((t + 1) & 16) ? Blo : Bhi) + kn;
    const f16* lA0 = &lds[(cur * 2 + 0) * 8192];
    const f16* lB0 = &lds[32768 + (cur * 2 + 0) * 8192];
    const f16* lA1 = &lds[(cur * 2 + 1) * 8192];
    const f16* lB1 = &lds[32768 + (cur * 2 + 1) * 8192];
    f16* sA0 = &lds[(nxt * 2 + 0) * 8192];
    f16* sB0 = &lds[32768 + (nxt * 2 + 0) * 8192];
    f16* sA1 = &lds[(nxt * 2 + 1) * 8192];
    f16* sB1 = &lds[32768 + (nxt * 2 + 1) * 8192];

    f16x8 a[8], b0, b1;

    // ---- phase 0
#pragma unroll
    for (int i = 0; i < 8; ++i) a[i] = *(const f16x8*)&lA0[offA[i]];
    b0 = *(const f16x8*)&lB0[offB[0]];
    b1 = *(const f16x8*)&lB0[offB[1]];
    if (st) { async16(&sA0[ldst0], An + gO0); async16(&sA0[ldst1], An + gO1); }
    __builtin_amdgcn_s_barrier();
    __builtin_amdgcn_s_setprio(1);
#pragma unroll
    for (int i = 0; i < 8; ++i) {
      acc[i][0] = MFMA16(a[i], b0, acc[i][0], 0, 0, 0);
      acc[i][1] = MFMA16(a[i], b1, acc[i][1], 0, 0, 0);
    }
    __builtin_amdgcn_s_setprio(0);
    __builtin_amdgcn_s_barrier();

    // ---- phase 1
    b0 = *(const f16x8*)&lB0[offB[2]];
    b1 = *(const f16x8*)&lB0[offB[3]];
    if (st) { async16(&sB0[ldst0], Bn + gO0); async16(&sB0[ldst1], Bn + gO1); }
    __builtin_amdgcn_s_barrier();
    __builtin_amdgcn_s_setprio(1);
#pragma unroll
    for (int i = 0; i < 8; ++i) {
      acc[i][2] = MFMA16(a[i], b0, acc[i][2], 0, 0, 0);
      acc[i][3] = MFMA16(a[i], b1, acc[i][3], 0, 0, 0);
    }
    __builtin_amdgcn_s_setprio(0);
    if (t == NT - 1) {
      asm volatile("s_waitcnt vmcnt(0)" ::: "memory");
    } else {
      asm volatile("s_waitcnt vmcnt(4)" ::: "memory");
    }
    __builtin_amdgcn_s_barrier();

    // ---- phase 2
#pragma unroll
    for (int i = 0; i < 8; ++i) a[i] = *(const f16x8*)&lA1[offA[i]];
    b0 = *(const f16x8*)&lB1[offB[0]];
    b1 = *(const f16x8*)&lB1[offB[1]];
    if (st) { async16(&sA1[ldst0], An + 32 + gO0); async16(&sA1[ldst1], An + 32 + gO1); }
    __builtin_amdgcn_s_barrier();
    __builtin_amdgcn_s_setprio(1);
#pragma unroll
    for (int i = 0; i < 8; ++i) {
      acc[i][0] = MFMA16(a[i], b0, acc[i][0], 0, 0, 0);
      acc[i][1] = MFMA16(a[i], b1, acc[i][1], 0, 0, 0);
    }
    __builtin_amdgcn_s_setprio(0);
    __builtin_amdgcn_s_barrier();

    // ---- phase 3
    b0 = *(const f16x8*)&lB1[offB[2]];
    b1 = *(const f16x8*)&lB1[offB[3]];
    if (st) { async16(&sB1[ldst0], Bn + 32 + gO0); async16(&sB1[ldst1], Bn + 32 + gO1); }
    __builtin_amdgcn_s_barrier();
    __builtin_amdgcn_s_setprio(1);
#pragma unroll
    for (int i = 0; i < 8; ++i) {
      acc[i][2] = MFMA16(a[i], b0, acc[i][2], 0, 0, 0);
      acc[i][3] = MFMA16(a[i], b1, acc[i][3], 0, 0, 0);
    }
    __builtin_amdgcn_s_setprio(0);
    asm volatile("s_waitcnt vmcnt(4)" ::: "memory");
    __builtin_amdgcn_s_barrier();
  }

  // -------------------- epilogue --------------------
  const int er0 = wm * 128 + qd * 4;
  const int ec0 = wn * 64 + frow;
  float bias[4];
#pragma unroll
  for (int jj = 0; jj < 4; ++jj) {
    const int c = colB0 + ec0 + jj * 16;
    bias[jj] = c < 1024 ? bq[c] : (c < 2048 ? bk[c - 1024] : bv[c - 2048]);
  }

  if (!ext) {
    if (colB0 < 1024) {  // q: hi+lo
#pragma unroll
      for (int jj = 0; jj < 4; ++jj) {
        const int c = colB0 + ec0 + jj * 16;
#pragma unroll
        for (int i = 0; i < 8; ++i)
#pragma unroll
          for (int r = 0; r < 4; ++r) {
            const int row = mrow0 + er0 + i * 16 + r;
            const float val = acc[i][jj][r] + bias[jj];
            const size_t idx = (size_t)row * HH + c;
            const f16 h = (f16)val;
            q_hi[idx] = h;
            q_lo[idx] = (f16)(val - (float)h);
          }
      }
    } else if (colB0 < 2048) {  // token k
#pragma unroll
      for (int jj = 0; jj < 4; ++jj) {
        const int c = colB0 + ec0 + jj * 16 - 1024;
#pragma unroll
        for (int i = 0; i < 8; ++i)
#pragma unroll
          for (int r = 0; r < 4; ++r) {
            const int row = mrow0 + er0 + i * 16 + r;
            kt[(size_t)row * HH + c] = (f16)(acc[i][jj][r] + bias[jj]);
          }
      }
    } else {  // token v
#pragma unroll
      for (int jj = 0; jj < 4; ++jj) {
        const int c = colB0 + ec0 + jj * 16 - 2048;
#pragma unroll
        for (int i = 0; i < 8; ++i)
#pragma unroll
          for (int r = 0; r < 4; ++r) {
            const int row = mrow0 + er0 + i * 16 + r;
            vt[(size_t)row * HH + c] = (f16)(acc[i][jj][r] + bias[jj]);
          }
      }
    }
  } else {
    if (colB0 < 2048) {  // ext k: hi+lo
#pragma unroll
      for (int jj = 0; jj < 4; ++jj) {
        const int c = colB0 + ec0 + jj * 16 - 1024;
#pragma unroll
        for (int i = 0; i < 8; ++i)
#pragma unroll
          for (int r = 0; r < 4; ++r) {
            const int row = mrow0 + er0 + i * 16 + r;
            const float val = acc[i][jj][r] + bias[jj];
            const size_t idx = (size_t)row * HH + c;
            const f16 h = (f16)val;
            ke_hi[idx] = h;
            ke_lo[idx] = (f16)(val - (float)h);
          }
      }
    } else {  // ext v -> veT[b][h][e], transposed via LDS in two h-halves
      f16* tl = lds;  // [128][264]
      const int b = mrow0 >> 9, e0 = mrow0 & 511;
      const int h0 = colB0 - 2048;
#pragma unroll
      for (int p = 0; p < 2; ++p) {
        __syncthreads();
        if ((wn >> 1) == p) {
          const int hL = (wn & 1) * 64 + frow;
#pragma unroll
          for (int jj = 0; jj < 4; ++jj)
#pragma unroll
            for (int i = 0; i < 8; ++i)
#pragma unroll
              for (int r = 0; r < 4; ++r) {
                const int e = er0 + i * 16 + r;
                tl[(hL + jj * 16) * 264 + e] = (f16)(acc[i][jj][r] + bias[jj]);
              }
        }
        __syncthreads();
        for (int c = tid; c < 128 * 32; c += 512) {
          const int hL = c >> 5, ch = c & 31;
          const f16x8 v = *(const f16x8*)&tl[hL * 264 + ch * 8];
          *(f16x8*)&veT[(size_t)(b * HH + h0 + p * 128 + hL) * EE + e0 + ch * 8] = v;
        }
      }
    }
  }
}

// ---------------------------------------------------------------------------
// Score GEMM, counted-vmcnt pipeline: s_part[kh][b][s][e] = q . ke (3 terms:
// qh*keh + qh*kel + ql*keh). Tile 256x128, K=512 (khalf split), 8 waves.
// Grid = 4n x 8m x 8(b,kh) = 256 blocks exactly -> single generation, no tail.
// LDS 96 KB: 2 buffers x (Ah 8192 | Al 8192 | Bh 4096 | Bl 4096) f16.
// 3 phases/k-step, one MFMA term each; regions staged in the phase where
// they're consumed next step. Per-thread queue depth 6; derived waits
// vmcnt(5)/(4)/(3) at phase ends (ledger-verified), never 0 mid-loop.
// ---------------------------------------------------------------------------
__global__ __launch_bounds__(512, 2) void score_kernel(
    const f16* __restrict__ q_hi, const f16* __restrict__ q_lo,
    const f16* __restrict__ ke_hi, const f16* __restrict__ ke_lo,
    float* __restrict__ s_part) {
  const int b = blockIdx.z & 3;
  const int khalf = blockIdx.z >> 2;
  const int mtile = blockIdx.y;  // 0..7 (256 rows of s)
  const int ntile = blockIdx.x;  // 0..3 (128 cols of e)

  __shared__ f16 lds[49152];  // 96 KB

  const int tid = threadIdx.x;
  const int wave = tid >> 6, lane = tid & 63;
  const int wm = wave >> 1, wn = wave & 1;
  const int frow = lane & 15, qd = lane >> 4;

  const size_t aoff = ((size_t)b * SS + mtile * 256) * HH + khalf * 512;
  const size_t boff = ((size_t)b * EE + ntile * 128) * HH + khalf * 512;
  const f16* Ah = q_hi + aoff;
  const f16* Al = q_lo + aoff;
  const f16* Bh = ke_hi + boff;
  const f16* Bl = ke_lo + boff;

  const int srow = tid >> 2;
  const int scol = ((tid & 3) ^ ((srow >> 1) & 3)) * 8;
  const size_t gA0 = (size_t)srow * HH + scol;
  const size_t gA1 = (size_t)(128 + srow) * HH + scol;
  const int ldstA0 = (wave * 64) * 8;
  const int ldstA1 = (512 + wave * 64) * 8;
  const int ldstB0 = (wave * 64) * 8;

  int offA[4], offB[4];
#pragma unroll
  for (int i = 0; i < 4; ++i) {
    const int r = wm * 64 + i * 16 + frow;
    offA[i] = r * 32 + ((qd ^ ((r >> 1) & 3)) * 8);
  }
#pragma unroll
  for (int jj = 0; jj < 4; ++jj) {
    const int r = wn * 64 + jj * 16 + frow;
    offB[jj] = r * 32 + ((qd ^ ((r >> 1) & 3)) * 8);
  }

  f32x4 acc[4][4];
#pragma unroll
  for (int i = 0; i < 4; ++i)
#pragma unroll
    for (int jj = 0; jj < 4; ++jj)
#pragma unroll
      for (int r = 0; r < 4; ++r) acc[i][jj][r] = 0.0f;

  // Prologue: stage t=0 in ledger order [Ah,Ah,Bh][Bl][Al,Al]
  {
    f16* dAh = &lds[0];
    f16* dAl = &lds[8192];
    f16* dBh = &lds[16384];
    f16* dBl = &lds[20480];
    async16(&dAh[ldstA0], Ah + gA0); async16(&dAh[ldstA1], Ah + gA1);
    async16(&dBh[ldstB0], Bh + gA0);
    async16(&dBl[ldstB0], Bl + gA0);
    async16(&dAl[ldstA0], Al + gA0); async16(&dAl[ldstA1], Al + gA1);
  }
  asm volatile("s_waitcnt vmcnt(3)" ::: "memory");  // Ah,Ah,Bh landed
  __builtin_amdgcn_s_barrier();

  for (int t = 0; t < 16; ++t) {
    const int cur = t & 1, nxt = cur ^ 1;
    const bool st = (t < 15);
    const int kk = (t + 1) * 32;
    const f16* lAh = &lds[cur * 24576];
    const f16* lAl = &lds[cur * 24576 + 8192];
    const f16* lBh = &lds[cur * 24576 + 16384];
    const f16* lBl = &lds[cur * 24576 + 20480];
    f16* sAh = &lds[nxt * 24576];
    f16* sAl = &lds[nxt * 24576 + 8192];
    f16* sBh = &lds[nxt * 24576 + 16384];
    f16* sBl = &lds[nxt * 24576 + 20480];

    f16x8 ah[4], bh[4], x[4];

    // ---- phase 0: read ah,bh; stage Ah(t+1)x2 + Bh(t+1); MFMA ah*bh
#pragma unroll
    for (int i = 0; i < 4; ++i) ah[i] = *(const f16x8*)&lAh[offA[i]];
#pragma unroll
    for (int jj = 0; jj < 4; ++jj) bh[jj] = *(const f16x8*)&lBh[offB[jj]];
    if (st) {
      async16(&sAh[ldstA0], Ah + kk + gA0); async16(&sAh[ldstA1], Ah + kk + gA1);
      async16(&sBh[ldstB0], Bh + kk + gA0);
    }
    __builtin_amdgcn_s_barrier();
    __builtin_amdgcn_s_setprio(1);
#pragma unroll
    for (int i = 0; i < 4; ++i)
#pragma unroll
      for (int jj = 0; jj < 4; ++jj)
        acc[i][jj] = MFMA16(ah[i], bh[jj], acc[i][jj], 0, 0, 0);
    __builtin_amdgcn_s_setprio(0);
    if (st) { asm volatile("s_waitcnt vmcnt(5)" ::: "memory"); }  // Bl(t) landed
    else    { asm volatile("s_waitcnt vmcnt(2)" ::: "memory"); }
    __builtin_amdgcn_s_barrier();

    // ---- phase 1: read bl; stage Bl(t+1); MFMA ah*bl
#pragma unroll
    for (int jj = 0; jj < 4; ++jj) x[jj] = *(const f16x8*)&lBl[offB[jj]];
    if (st) async16(&sBl[ldstB0], Bl + kk + gA0);
    __builtin_amdgcn_s_barrier();
    __builtin_amdgcn_s_setprio(1);
#pragma unroll
    for (int i = 0; i < 4; ++i)
#pragma unroll
      for (int jj = 0; jj < 4; ++jj)
        acc[i][jj] = MFMA16(ah[i], x[jj], acc[i][jj], 0, 0, 0);
    __builtin_amdgcn_s_setprio(0);
    if (st) { asm volatile("s_waitcnt vmcnt(4)" ::: "memory"); }  // Al(t)x2 landed
    else    { asm volatile("s_waitcnt vmcnt(0)" ::: "memory"); }
    __builtin_amdgcn_s_barrier();

    // ---- phase 2: read al; stage Al(t+1)x2; MFMA al*bh
#pragma unroll
    for (int i = 0; i < 4; ++i) x[i] = *(const f16x8*)&lAl[offA[i]];
    if (st) { async16(&sAl[ldstA0], Al + kk + gA0); async16(&sAl[ldstA1], Al + kk + gA1); }
    __builtin_amdgcn_s_barrier();
    __builtin_amdgcn_s_setprio(1);
#pragma unroll
    for (int i = 0; i < 4; ++i)
#pragma unroll
      for (int jj = 0; jj < 4; ++jj)
        acc[i][jj] = MFMA16(x[i], bh[jj], acc[i][jj], 0, 0, 0);
    __builtin_amdgcn_s_setprio(0);
    if (st) { asm volatile("s_waitcnt vmcnt(3)" ::: "memory"); }  // Ah,Bh(t+1) landed
    __builtin_amdgcn_s_barrier();
  }

  // epilogue: scalar f32 stores
  float* dst = s_part + (size_t)khalf * BB * SS * EE + (size_t)b * SS * EE;
#pragma unroll
  for (int jj = 0; jj < 4; ++jj) {
    const int e = ntile * 128 + wn * 64 + jj * 16 + frow;
#pragma unroll
    for (int i = 0; i < 4; ++i)
#pragma unroll
      for (int r = 0; r < 4; ++r) {
        const int s = mtile * 256 + wm * 64 + i * 16 + qd * 4 + r;
        dst[(size_t)s * EE + e] = acc[i][jj][r];
      }
  }
}

// Fused selfdot + softmax (unchanged)
__global__ __launch_bounds__(256) void softmax_kernel(
    const f16* __restrict__ q_hi, const f16* __restrict__ q_lo,
    const f16* __restrict__ kt, const float* __restrict__ s_part,
    f16* __restrict__ probs, float* __restrict__ p_self) {
  const int t = blockIdx.x * 4 + (threadIdx.x >> 6);
  const int lane = threadIdx.x & 63;

  const size_t base = (size_t)t * HH;
  float ss = 0.f;
#pragma unroll
  for (int it = 0; it < 4; ++it) {
    const int off = it * 256 + lane * 4;
    const f16x4 qh = *(const f16x4*)&q_hi[base + off];
    const f16x4 ql = *(const f16x4*)&q_lo[base + off];
    const f16x4 kh = *(const f16x4*)&kt[base + off];
    ss += ((float)qh.x + (float)ql.x) * (float)kh.x;
    ss += ((float)qh.y + (float)ql.y) * (float)kh.y;
    ss += ((float)qh.z + (float)ql.z) * (float)kh.z;
    ss += ((float)qh.w + (float)ql.w) * (float)kh.w;
  }
#pragma unroll
  for (int m = 32; m > 0; m >>= 1) ss += __shfl_xor(ss, m, 64);

  const float* r0 = s_part + (size_t)t * EE;
  const float* r1 = s_part + (size_t)BB * SS * EE + (size_t)t * EE;
  const float4 a0 = *(const float4*)&r0[lane * 4];
  const float4 a1 = *(const float4*)&r0[256 + lane * 4];
  const float4 c0 = *(const float4*)&r1[lane * 4];
  const float4 c1 = *(const float4*)&r1[256 + lane * 4];
  const float v0x = a0.x + c0.x, v0y = a0.y + c0.y, v0z = a0.z + c0.z, v0w = a0.w + c0.w;
  const float v1x = a1.x + c1.x, v1y = a1.y + c1.y, v1z = a1.z + c1.z, v1w = a1.w + c1.w;
  float m = fmaxf(fmaxf(fmaxf(v0x, v0y), fmaxf(v0z, v0w)),
                  fmaxf(fmaxf(v1x, v1y), fmaxf(v1z, v1w)));
#pragma unroll
  for (int sh = 32; sh > 0; sh >>= 1) m = fmaxf(m, __shfl_xor(m, sh, 64));
  m = fmaxf(m, ss);
  const float e0 = __expf(v0x - m), e1 = __expf(v0y - m);
  const float e2 = __expf(v0z - m), e3 = __expf(v0w - m);
  const float e4 = __expf(v1x - m), e5 = __expf(v1y - m);
  const float e6 = __expf(v1z - m), e7 = __expf(v1w - m);
  float sum = ((e0 + e1) + (e2 + e3)) + ((e4 + e5) + (e6 + e7));
#pragma unroll
  for (int sh = 32; sh > 0; sh >>= 1) sum += __shfl_xor(sum, sh, 64);
  const float es = __expf(ss - m);
  const float inv = 1.0f / (sum + es);
  f16x4 p0, p1;
  p0.x = (f16)(e0 * inv); p0.y = (f16)(e1 * inv);
  p0.z = (f16)(e2 * inv); p0.w = (f16)(e3 * inv);
  p1.x = (f16)(e4 * inv); p1.y = (f16)(e5 * inv);
  p1.z = (f16)(e6 * inv); p1.w = (f16)(e7 * inv);
  *(f16x4*)&probs[(size_t)t * EE + lane * 4] = p0;
  *(f16x4*)&probs[(size_t)t * EE + 256 + lane * 4] = p1;
  if (lane == 0) p_self[t] = es * inv;
}

// ---------------------------------------------------------------------------
// PV GEMM, counted-vmcnt pipeline: out[b,s,h] = probs . veT^T + p_self*v_tok.
// Tile 256x128 (s x h), K=512 (e), TERMS=1, 8 waves.
// Grid = 8n x 8m x 4b = 256 blocks exactly. Triple-buffered LDS (72 KB),
// depth-2 staging: during step t stage step t+2 (A in ph0, B in ph1); one
// wait vmcnt(3) per step lands step t+1's 3 loads (queue depth 6).
// ---------------------------------------------------------------------------
__global__ __launch_bounds__(512, 2) void pv_kernel(
    const f16* __restrict__ probs, const f16* __restrict__ veT,
    const float* __restrict__ p_self, const f16* __restrict__ vt,
    float* __restrict__ out) {
  const int b = blockIdx.z;
  const int mtile = blockIdx.y;  // 0..7 (256 rows of s)
  const int ntile = blockIdx.x;  // 0..7 (128 cols of h)

  __shared__ f16 lds[36864];  // 72 KB: 3 x (A 8192 | B 4096)

  const int tid = threadIdx.x;
  const int wave = tid >> 6, lane = tid & 63;
  const int wm = wave >> 1, wn = wave & 1;
  const int frow = lane & 15, qd = lane >> 4;

  const size_t aoff = ((size_t)b * SS + mtile * 256) * EE;
  const size_t boff = ((size_t)b * HH + ntile * 128) * EE;
  const f16* A = probs + aoff;
  const f16* Bv = veT + boff;

  const int srow = tid >> 2;
  const int scol = ((tid & 3) ^ ((srow >> 1) & 3)) * 8;
  const size_t gA0 = (size_t)srow * EE + scol;
  const size_t gA1 = (size_t)(128 + srow) * EE + scol;
  const int ldstA0 = (wave * 64) * 8;
  const int ldstA1 = (512 + wave * 64) * 8;
  const int ldstB0 = (wave * 64) * 8;

  int offA[4], offB[4];
#pragma unroll
  for (int i = 0; i < 4; ++i) {
    const int r = wm * 64 + i * 16 + frow;
    offA[i] = r * 32 + ((qd ^ ((r >> 1) & 3)) * 8);
  }
#pragma unroll
  for (int jj = 0; jj < 4; ++jj) {
    const int r = wn * 64 + jj * 16 + frow;
    offB[jj] = r * 32 + ((qd ^ ((r >> 1) & 3)) * 8);
  }

  f32x4 acc[4][4];
#pragma unroll
  for (int i = 0; i < 4; ++i)
#pragma unroll
    for (int jj = 0; jj < 4; ++jj)
#pragma unroll
      for (int r = 0; r < 4; ++r) acc[i][jj][r] = 0.0f;

  // Prologue: stage t=0 and t=1 (order A,A,B per step)
  {
    f16* dA0 = &lds[0], *dB0 = &lds[8192];
    f16* dA1 = &lds[12288], *dB1 = &lds[12288 + 8192];
    async16(&dA0[ldstA0], A + gA0); async16(&dA0[ldstA1], A + gA1);
    async16(&dB0[ldstB0], Bv + gA0);
    async16(&dA1[ldstA0], A + 32 + gA0); async16(&dA1[ldstA1], A + 32 + gA1);
    async16(&dB1[ldstB0], Bv + 32 + gA0);
  }
  asm volatile("s_waitcnt vmcnt(3)" ::: "memory");  // t=0's 3 landed
  __builtin_amdgcn_s_barrier();

  int cur = 0, stg = 2;
  for (int t = 0; t < 16; ++t) {
    const bool st = (t < 14);
    const int kk = (t + 2) * 32;
    const f16* lA = &lds[cur * 12288];
    const f16* lB = &lds[cur * 12288 + 8192];
    f16* sA = &lds[stg * 12288];
    f16* sB = &lds[stg * 12288 + 8192];

    f16x8 a[4], b[4];

    // ---- phase 0: read a[4], b[0..1]; stage A(t+2)x2; MFMA j=0,1
#pragma unroll
    for (int i = 0; i < 4; ++i) a[i] = *(const f16x8*)&lA[offA[i]];
    b[0] = *(const f16x8*)&lB[offB[0]];
    b[1] = *(const f16x8*)&lB[offB[1]];
    if (st) { async16(&sA[ldstA0], A + kk + gA0); async16(&sA[ldstA1], A + kk + gA1); }
    __builtin_amdgcn_s_barrier();
    __builtin_amdgcn_s_setprio(1);
#pragma unroll
    for (int i = 0; i < 4; ++i) {
      acc[i][0] = MFMA16(a[i], b[0], acc[i][0], 0, 0, 0);
      acc[i][1] = MFMA16(a[i], b[1], acc[i][1], 0, 0, 0);
    }
    __builtin_amdgcn_s_setprio(0);
    __builtin_amdgcn_s_barrier();

    // ---- phase 1: read b[2..3]; stage B(t+2); MFMA j=2,3
    b[2] = *(const f16x8*)&lB[offB[2]];
    b[3] = *(const f16x8*)&lB[offB[3]];
    if (st) async16(&sB[ldstB0], Bv + kk + gA0);
    __builtin_amdgcn_s_barrier();
    __builtin_amdgcn_s_setprio(1);
#pragma unroll
    for (int i = 0; i < 4; ++i) {
      acc[i][2] = MFMA16(a[i], b[2], acc[i][2], 0, 0, 0);
      acc[i][3] = MFMA16(a[i], b[3], acc[i][3], 0, 0, 0);
    }
    __builtin_amdgcn_s_setprio(0);
    if (t < 14)      { asm volatile("s_waitcnt vmcnt(3)" ::: "memory"); }  // t+1 landed
    else if (t == 14){ asm volatile("s_waitcnt vmcnt(0)" ::: "memory"); }
    __builtin_amdgcn_s_barrier();

    cur = (cur == 2) ? 0 : cur + 1;
    stg = (stg == 2) ? 0 : stg + 1;
  }

  // epilogue
#pragma unroll
  for (int jj = 0; jj < 4; ++jj) {
    const int h = ntile * 128 + wn * 64 + jj * 16 + frow;
#pragma unroll
    for (int i = 0; i < 4; ++i)
#pragma unroll
      for (int r = 0; r < 4; ++r) {
        const int s = mtile * 256 + wm * 64 + i * 16 + qd * 4 + r;
        const size_t t = (size_t)b * SS + s;
        __builtin_nontemporal_store(
            acc[i][jj][r] + p_self[t] * (float)vt[t * HH + h], &out[t * HH + h]);
      }
  }
}

extern "C" void kernel_launch(void* const* d_in, const int* in_sizes, int n_in,
                              void* d_out, int out_size, void* d_ws, size_t ws_size,
                              hipStream_t stream) {
  const float* hidden = (const float*)d_in[0];
  const float* ext    = (const float*)d_in[1];
  const float* Wq = (const float*)d_in[2];
  const float* bq = (const float*)d_in[3];
  const float* Wk = (const float*)d_in[4];
  const float* bk = (const float*)d_in[5];
  const float* Wv = (const float*)d_in[6];
  const float* bv = (const float*)d_in[7];
  float* out = (float*)d_out;

  char* ws = (char*)d_ws;
  size_t off = 0;
  auto alloc = [&](size_t bytes) {
    char* p = ws + off;
    off += (bytes + 255) & ~(size_t)255;
    return p;
  };
  const size_t TOK = 8192, EXT = 2048;
  f16* xh    = (f16*)alloc(TOK * HH * 2);
  f16* xe    = (f16*)alloc(EXT * HH * 2);
  f16* wt_hi = (f16*)alloc(3072ull * HH * 2);
  f16* wt_lo = (f16*)alloc(3072ull * HH * 2);
  f16* q_hi  = (f16*)alloc(TOK * HH * 2);
  f16* q_lo  = (f16*)alloc(TOK * HH * 2);
  f16* kt    = (f16*)alloc(TOK * HH * 2);
  f16* vt    = (f16*)alloc(TOK * HH * 2);
  f16* ke_hi = (f16*)alloc(EXT * HH * 2);
  f16* ke_lo = (f16*)alloc(EXT * HH * 2);
  f16* veT   = (f16*)alloc((size_t)BB * HH * EE * 2);
  float* p_self = (float*)alloc(TOK * 4);
  float* s_part = (float*)alloc(2ull * BB * SS * EE * 4);
  f16* probs    = (f16*)alloc((size_t)BB * SS * EE * 2);

  // 1. cast A-side inputs to fp16; transpose+split W hi/lo
  cast_kernel<<<10240, 256, 0, stream>>>(hidden, ext, xh, xe);
  wsplit_kernel<<<dim3(32, 96), dim3(32, 8), 0, stream>>>(Wq, Wk, Wv, wt_hi, wt_lo);

  // 2. fused projection GEMM, 256^2 8-phase counted-vmcnt schedule
  proj_kernel<<<448, 512, 0, stream>>>(
      xh, xe, wt_hi, wt_lo, bq, bk, bv,
      q_hi, q_lo, kt, vt, ke_hi, ke_lo, veT);

  // 3. attention (score & pv now 256-block counted-vmcnt pipelines)
  score_kernel<<<dim3(4, 8, 8), 512, 0, stream>>>(q_hi, q_lo, ke_hi, ke_lo, s_part);
  softmax_kernel<<<2048, 256, 0, stream>>>(q_hi, q_lo, kt, s_part, probs, p_self);
  pv_kernel<<<dim3(8, 8, 4), 512, 0, stream>>>(probs, veT, p_self, vt, out);
}